// Round 1
// baseline (484.233 us; speedup 1.0000x reference)
//
#include <hip/hip_runtime.h>
#include <hip/hip_bf16.h>

#define NN 8192
#define FIN 256
#define FO 128
#define KSPLIT 8
#define JCHUNK (NN / KSPLIT)   // 1024
#define L2E 1.4426950408889634f

typedef __bf16 bf16x8 __attribute__((ext_vector_type(8)));
typedef __bf16 bf16x2 __attribute__((ext_vector_type(2)));
typedef float  f32x4  __attribute__((ext_vector_type(4)));

// ---------------------------------------------------------------------------
// Kernel 1: h = x@W (fp32), write hT (bf16, transposed 128 x 8192),
//           f_src = h@a_src, f_dst = h@a_dst (fp32).
// 512 blocks x 256 threads, 16 rows per block.
// ---------------------------------------------------------------------------
__global__ __launch_bounds__(256) void k_proj(
    const float* __restrict__ x, const float* __restrict__ W,
    const float* __restrict__ a_src, const float* __restrict__ a_dst,
    __bf16* __restrict__ hT, float* __restrict__ f_src, float* __restrict__ f_dst)
{
  __shared__ float xs[16 * FIN];     // 16 KB x-tile
  __shared__ float fs[16], fd[16];
  const int tid = threadIdx.x;
  const int i0 = blockIdx.x * 16;

  const float4* xg = (const float4*)(x + (size_t)i0 * FIN);
  float4* xs4 = (float4*)xs;
  #pragma unroll
  for (int t = 0; t < 4; t++) xs4[tid + 256 * t] = xg[tid + 256 * t];
  if (tid < 16) { fs[tid] = 0.f; fd[tid] = 0.f; }
  __syncthreads();

  const int cq = tid & 31;    // column quad: cols c0..c0+3
  const int rg = tid >> 5;    // row group: rows r0, r0+1
  const int c0 = cq * 4;
  const int r0 = rg * 2;
  float acc0[4] = {0.f,0.f,0.f,0.f};
  float acc1[4] = {0.f,0.f,0.f,0.f};
  const float* xr0 = xs + r0 * FIN;
  const float* xr1 = xs + (r0 + 1) * FIN;

  for (int k = 0; k < FIN; k += 4) {
    float4 xa = *(const float4*)(xr0 + k);
    float4 xb = *(const float4*)(xr1 + k);
    #pragma unroll
    for (int kk = 0; kk < 4; kk++) {
      float4 wv = *(const float4*)(W + (size_t)(k + kk) * FO + c0);
      float xav = ((const float*)&xa)[kk];
      float xbv = ((const float*)&xb)[kk];
      acc0[0] += xav * wv.x; acc0[1] += xav * wv.y;
      acc0[2] += xav * wv.z; acc0[3] += xav * wv.w;
      acc1[0] += xbv * wv.x; acc1[1] += xbv * wv.y;
      acc1[2] += xbv * wv.z; acc1[3] += xbv * wv.w;
    }
  }

  // f partials from fp32 h (before bf16 rounding)
  float4 as = *(const float4*)(a_src + c0);
  float4 ad = *(const float4*)(a_dst + c0);
  float ps0 = acc0[0]*as.x + acc0[1]*as.y + acc0[2]*as.z + acc0[3]*as.w;
  float ps1 = acc1[0]*as.x + acc1[1]*as.y + acc1[2]*as.z + acc1[3]*as.w;
  float pd0 = acc0[0]*ad.x + acc0[1]*ad.y + acc0[2]*ad.z + acc0[3]*ad.w;
  float pd1 = acc1[0]*ad.x + acc1[1]*ad.y + acc1[2]*ad.z + acc1[3]*ad.w;
  atomicAdd(&fs[r0],     ps0);
  atomicAdd(&fs[r0 + 1], ps1);
  atomicAdd(&fd[r0],     pd0);
  atomicAdd(&fd[r0 + 1], pd1);

  // hT bf16 writes (transposed): hT[col][row]
  #pragma unroll
  for (int c = 0; c < 4; c++) {
    bf16x2 v;
    v[0] = (__bf16)acc0[c];
    v[1] = (__bf16)acc1[c];
    *(bf16x2*)(hT + (size_t)(c0 + c) * NN + i0 + r0) = v;
  }
  __syncthreads();
  if (tid < 16) { f_src[i0 + tid] = fs[tid]; f_dst[i0 + tid] = fd[tid]; }
}

// ---------------------------------------------------------------------------
// Kernel 2: fused masked-softmax-weight construction + P@H via bf16 MFMA.
// P A-fragments built directly in registers from streaming adj reads.
// No __syncthreads in the K loop. 2048 blocks x 128 threads (2 waves),
// wave = 16 rows x 128 cols, K-chunk = 1024 j. Partials via atomicAdd.
// ---------------------------------------------------------------------------
__global__ __launch_bounds__(128, 4) void k_attn(
    const float* __restrict__ adj, const __bf16* __restrict__ hT,
    const float* __restrict__ f_src, const float* __restrict__ f_dst,
    float* __restrict__ num, float* __restrict__ lsum)
{
  __shared__ float dls[2 * JCHUNK];   // 8 KB: interleaved d*log2e, d*0.2*log2e
  const int tid = threadIdx.x;
  const int rb = blockIdx.x >> 3;     // 0..255 row block (32 rows)
  const int ks = blockIdx.x & 7;      // k-split
  const int jbase = ks * JCHUNK;

  for (int t = tid; t < JCHUNK; t += 128) {
    float d = f_dst[jbase + t];
    dls[2 * t]     = d * L2E;
    dls[2 * t + 1] = d * (0.2f * L2E);
  }

  const int wv = tid >> 6;
  const int lane = tid & 63;
  const int m = lane & 15;     // A row within tile / B col within n-tile
  const int q = lane >> 4;     // quad: k-slice q*8..q*8+7
  const int i0 = rb * 32 + wv * 16;
  const float s  = f_src[i0 + m];
  const float s1 = s * L2E;
  const float s2 = s * (0.2f * L2E);
  __syncthreads();

  f32x4 acc[8];
  #pragma unroll
  for (int t = 0; t < 8; t++) acc[t] = (f32x4){0.f, 0.f, 0.f, 0.f};
  float psum = 0.f;

  const float*  adjp = adj + (size_t)(i0 + m) * NN + jbase + q * 8;
  const __bf16* hb   = hT + (size_t)m * NN + jbase + q * 8;

  #pragma unroll 2
  for (int st = 0; st < JCHUNK / 32; st++) {
    const int koff = st * 32;
    float4 a0 = *(const float4*)(adjp + koff);
    float4 a1 = *(const float4*)(adjp + koff + 4);
    const float4* dp = (const float4*)(dls + 2 * (koff + q * 8));
    float4 d0 = dp[0], d1 = dp[1], d2 = dp[2], d3 = dp[3];

    float e0 = __builtin_amdgcn_exp2f(fmaxf(s1 + d0.x, s2 + d0.y));
    float e1 = __builtin_amdgcn_exp2f(fmaxf(s1 + d0.z, s2 + d0.w));
    float e2 = __builtin_amdgcn_exp2f(fmaxf(s1 + d1.x, s2 + d1.y));
    float e3 = __builtin_amdgcn_exp2f(fmaxf(s1 + d1.z, s2 + d1.w));
    float e4 = __builtin_amdgcn_exp2f(fmaxf(s1 + d2.x, s2 + d2.y));
    float e5 = __builtin_amdgcn_exp2f(fmaxf(s1 + d2.z, s2 + d2.w));
    float e6 = __builtin_amdgcn_exp2f(fmaxf(s1 + d3.x, s2 + d3.y));
    float e7 = __builtin_amdgcn_exp2f(fmaxf(s1 + d3.z, s2 + d3.w));
    float p0 = (a0.x > 0.f) ? e0 : 0.f;
    float p1 = (a0.y > 0.f) ? e1 : 0.f;
    float p2 = (a0.z > 0.f) ? e2 : 0.f;
    float p3 = (a0.w > 0.f) ? e3 : 0.f;
    float p4 = (a1.x > 0.f) ? e4 : 0.f;
    float p5 = (a1.y > 0.f) ? e5 : 0.f;
    float p6 = (a1.z > 0.f) ? e6 : 0.f;
    float p7 = (a1.w > 0.f) ? e7 : 0.f;
    psum += ((p0 + p1) + (p2 + p3)) + ((p4 + p5) + (p6 + p7));

    bf16x8 af;
    af[0] = (__bf16)p0; af[1] = (__bf16)p1; af[2] = (__bf16)p2; af[3] = (__bf16)p3;
    af[4] = (__bf16)p4; af[5] = (__bf16)p5; af[6] = (__bf16)p6; af[7] = (__bf16)p7;

    #pragma unroll
    for (int nt = 0; nt < 8; nt++) {
      bf16x8 bfrag = *(const bf16x8*)(hb + (size_t)nt * 16 * NN + koff);
      acc[nt] = __builtin_amdgcn_mfma_f32_16x16x32_bf16(af, bfrag, acc[nt], 0, 0, 0);
    }
  }

  // denominator: rows keyed by m live in lanes {m, m+16, m+32, m+48}
  psum += __shfl_xor(psum, 16);
  psum += __shfl_xor(psum, 32);
  if (lane < 16) atomicAdd(&lsum[i0 + lane], psum);

  // numerator: C/D layout row=(lane>>4)*4+r, col=lane&15
  #pragma unroll
  for (int nt = 0; nt < 8; nt++) {
    #pragma unroll
    for (int r = 0; r < 4; r++) {
      atomicAdd(&num[(size_t)(i0 + q * 4 + r) * FO + nt * 16 + m], acc[nt][r]);
    }
  }
}

// ---------------------------------------------------------------------------
// Kernel 3: out = num / l, vectorized float4.
// ---------------------------------------------------------------------------
__global__ __launch_bounds__(256) void k_div(
    const float* __restrict__ num, const float* __restrict__ lsum,
    float* __restrict__ out)
{
  int idx = blockIdx.x * 256 + threadIdx.x;        // float4 index
  float4 v = ((const float4*)num)[idx];
  float inv = 1.0f / lsum[idx >> 5];               // 32 float4 per row
  float4 o;
  o.x = v.x * inv; o.y = v.y * inv; o.z = v.z * inv; o.w = v.w * inv;
  ((float4*)out)[idx] = o;
}

extern "C" void kernel_launch(void* const* d_in, const int* in_sizes, int n_in,
                              void* d_out, int out_size, void* d_ws, size_t ws_size,
                              hipStream_t stream) {
  const float* x     = (const float*)d_in[0];
  const float* adj   = (const float*)d_in[1];
  const float* W     = (const float*)d_in[2];
  const float* a_src = (const float*)d_in[3];
  const float* a_dst = (const float*)d_in[4];
  float* out = (float*)d_out;

  char* ws = (char*)d_ws;
  __bf16* hT   = (__bf16*)ws;                                  // 2 MB
  float* f_src = (float*)(ws + 2097152);                       // 32 KB
  float* f_dst = (float*)(ws + 2097152 + 32768);               // 32 KB
  float* num   = (float*)(ws + 2097152 + 65536);               // 4 MB
  float* lsum  = (float*)(ws + 2097152 + 65536 + 4194304);     // 32 KB

  hipMemsetAsync(num, 0, 4194304 + 32768, stream);             // zero num + lsum
  hipLaunchKernelGGL(k_proj, dim3(512), dim3(256), 0, stream,
                     x, W, a_src, a_dst, hT, f_src, f_dst);
  hipLaunchKernelGGL(k_attn, dim3(2048), dim3(128), 0, stream,
                     adj, hT, f_src, f_dst, num, lsum);
  hipLaunchKernelGGL(k_div, dim3(1024), dim3(256), 0, stream,
                     num, lsum, out);
}

// Round 2
// 461.559 us; speedup vs baseline: 1.0491x; 1.0491x over previous
//
#include <hip/hip_runtime.h>
#include <hip/hip_bf16.h>

#define NN 8192
#define FIN 256
#define FO 128
#define KSPLIT 8
#define JCHUNK (NN / KSPLIT)   // 1024
#define L2E 1.4426950408889634f

typedef __bf16 bf16x8 __attribute__((ext_vector_type(8)));
typedef __bf16 bf16x2 __attribute__((ext_vector_type(2)));
typedef float  f32x4  __attribute__((ext_vector_type(4)));

// ---------------------------------------------------------------------------
// Kernel 1: h = x@W (fp32 accum), write Bpack (bf16 MFMA-B-fragment layout),
//           f_src = h@a_src, f_dst = h@a_dst (fp32).
// Bpack element (kg, nt, lane=q*16+m, t) = h[j = kg*32+q*8+t][n = nt*16+m]
// so a wave's B-frag load is one contiguous 1 KB dwordx4.
// ---------------------------------------------------------------------------
__global__ __launch_bounds__(256) void k_proj(
    const float* __restrict__ x, const float* __restrict__ W,
    const float* __restrict__ a_src, const float* __restrict__ a_dst,
    __bf16* __restrict__ Bp, float* __restrict__ f_src, float* __restrict__ f_dst)
{
  __shared__ float xs[16 * FIN];     // 16 KB x-tile
  __shared__ float fs[16], fd[16];
  const int tid = threadIdx.x;
  const int i0 = blockIdx.x * 16;

  const float4* xg = (const float4*)(x + (size_t)i0 * FIN);
  float4* xs4 = (float4*)xs;
  #pragma unroll
  for (int t = 0; t < 4; t++) xs4[tid + 256 * t] = xg[tid + 256 * t];
  if (tid < 16) { fs[tid] = 0.f; fd[tid] = 0.f; }
  __syncthreads();

  const int cq = tid & 31;    // column quad: cols c0..c0+3
  const int rg = tid >> 5;    // row group: rows r0, r0+1
  const int c0 = cq * 4;
  const int r0 = rg * 2;
  float acc0[4] = {0.f,0.f,0.f,0.f};
  float acc1[4] = {0.f,0.f,0.f,0.f};
  const float* xr0 = xs + r0 * FIN;
  const float* xr1 = xs + (r0 + 1) * FIN;

  for (int k = 0; k < FIN; k += 4) {
    float4 xa = *(const float4*)(xr0 + k);
    float4 xb = *(const float4*)(xr1 + k);
    #pragma unroll
    for (int kk = 0; kk < 4; kk++) {
      float4 wv = *(const float4*)(W + (size_t)(k + kk) * FO + c0);
      float xav = ((const float*)&xa)[kk];
      float xbv = ((const float*)&xb)[kk];
      acc0[0] += xav * wv.x; acc0[1] += xav * wv.y;
      acc0[2] += xav * wv.z; acc0[3] += xav * wv.w;
      acc1[0] += xbv * wv.x; acc1[1] += xbv * wv.y;
      acc1[2] += xbv * wv.z; acc1[3] += xbv * wv.w;
    }
  }

  // f partials from fp32 h (before bf16 rounding)
  float4 as = *(const float4*)(a_src + c0);
  float4 ad = *(const float4*)(a_dst + c0);
  float ps0 = acc0[0]*as.x + acc0[1]*as.y + acc0[2]*as.z + acc0[3]*as.w;
  float ps1 = acc1[0]*as.x + acc1[1]*as.y + acc1[2]*as.z + acc1[3]*as.w;
  float pd0 = acc0[0]*ad.x + acc0[1]*ad.y + acc0[2]*ad.z + acc0[3]*ad.w;
  float pd1 = acc1[0]*ad.x + acc1[1]*ad.y + acc1[2]*ad.z + acc1[3]*ad.w;
  atomicAdd(&fs[r0],     ps0);
  atomicAdd(&fs[r0 + 1], ps1);
  atomicAdd(&fd[r0],     pd0);
  atomicAdd(&fd[r0 + 1], pd1);

  // Bpack bf16x2 writes: rows j0=i0+r0 (t even) and j0+1 (t+1), col n=c0+c
  const int j0 = i0 + r0;
  const int kg = j0 >> 5;
  const int q  = (j0 >> 3) & 3;
  const int t0 = j0 & 7;
  #pragma unroll
  for (int c = 0; c < 4; c++) {
    const int n = c0 + c;
    bf16x2 v;
    v[0] = (__bf16)acc0[c];
    v[1] = (__bf16)acc1[c];
    size_t idx = ((size_t)(kg * 8 + (n >> 4)) * 64 + q * 16 + (n & 15)) * 8 + t0;
    *(bf16x2*)(Bp + idx) = v;
  }
  __syncthreads();
  if (tid < 16) { f_src[i0 + tid] = fs[tid]; f_dst[i0 + tid] = fd[tid]; }
}

// ---------------------------------------------------------------------------
// Kernel 2: fused masked-softmax-weight construction + P@H via bf16 MFMA.
// P A-fragments built in registers from streaming adj; B-fragments are
// single contiguous 1KB coalesced loads from Bpack (no scatter, no LDS).
// 1024 blocks x 256 threads (4 waves, 64 rows/block), K-chunk = 1024 j.
// ---------------------------------------------------------------------------
__global__ __launch_bounds__(256, 4) void k_attn(
    const float* __restrict__ adj, const __bf16* __restrict__ Bp,
    const float* __restrict__ f_src, const float* __restrict__ f_dst,
    float* __restrict__ num, float* __restrict__ lsum)
{
  __shared__ float dls[2 * JCHUNK];   // 8 KB: interleaved d*log2e, d*0.2*log2e
  const int tid = threadIdx.x;
  const int rb = blockIdx.x >> 3;     // 0..127 row block (64 rows)
  const int ks = blockIdx.x & 7;      // k-split
  const int jbase = ks * JCHUNK;

  for (int t = tid; t < JCHUNK; t += 256) {
    float d = f_dst[jbase + t];
    dls[2 * t]     = d * L2E;
    dls[2 * t + 1] = d * (0.2f * L2E);
  }

  const int wv = tid >> 6;
  const int lane = tid & 63;
  const int m = lane & 15;     // A row within tile / B col within n-tile
  const int q = lane >> 4;     // quad: k-slice q*8..q*8+7
  const int i0 = rb * 64 + wv * 16;
  const float s  = f_src[i0 + m];
  const float s1 = s * L2E;
  const float s2 = s * (0.2f * L2E);
  __syncthreads();

  f32x4 acc[8];
  #pragma unroll
  for (int t = 0; t < 8; t++) acc[t] = (f32x4){0.f, 0.f, 0.f, 0.f};
  float psum = 0.f;

  const float*  adjp = adj + (size_t)(i0 + m) * NN + jbase + q * 8;
  const __bf16* bb   = Bp + (size_t)(ks * (JCHUNK / 32)) * 4096 + lane * 8;

  #pragma unroll 2
  for (int st = 0; st < JCHUNK / 32; st++) {
    const int koff = st * 32;
    float4 a0 = *(const float4*)(adjp + koff);
    float4 a1 = *(const float4*)(adjp + koff + 4);
    const float4* dp = (const float4*)(dls + 2 * (koff + q * 8));
    float4 d0 = dp[0], d1 = dp[1], d2 = dp[2], d3 = dp[3];

    float e0 = __builtin_amdgcn_exp2f(fmaxf(s1 + d0.x, s2 + d0.y));
    float e1 = __builtin_amdgcn_exp2f(fmaxf(s1 + d0.z, s2 + d0.w));
    float e2 = __builtin_amdgcn_exp2f(fmaxf(s1 + d1.x, s2 + d1.y));
    float e3 = __builtin_amdgcn_exp2f(fmaxf(s1 + d1.z, s2 + d1.w));
    float e4 = __builtin_amdgcn_exp2f(fmaxf(s1 + d2.x, s2 + d2.y));
    float e5 = __builtin_amdgcn_exp2f(fmaxf(s1 + d2.z, s2 + d2.w));
    float e6 = __builtin_amdgcn_exp2f(fmaxf(s1 + d3.x, s2 + d3.y));
    float e7 = __builtin_amdgcn_exp2f(fmaxf(s1 + d3.z, s2 + d3.w));
    float p0 = (a0.x > 0.f) ? e0 : 0.f;
    float p1 = (a0.y > 0.f) ? e1 : 0.f;
    float p2 = (a0.z > 0.f) ? e2 : 0.f;
    float p3 = (a0.w > 0.f) ? e3 : 0.f;
    float p4 = (a1.x > 0.f) ? e4 : 0.f;
    float p5 = (a1.y > 0.f) ? e5 : 0.f;
    float p6 = (a1.z > 0.f) ? e6 : 0.f;
    float p7 = (a1.w > 0.f) ? e7 : 0.f;
    psum += ((p0 + p1) + (p2 + p3)) + ((p4 + p5) + (p6 + p7));

    bf16x8 af;
    af[0] = (__bf16)p0; af[1] = (__bf16)p1; af[2] = (__bf16)p2; af[3] = (__bf16)p3;
    af[4] = (__bf16)p4; af[5] = (__bf16)p5; af[6] = (__bf16)p6; af[7] = (__bf16)p7;

    const __bf16* bs = bb + (size_t)st * 4096;
    #pragma unroll
    for (int nt = 0; nt < 8; nt++) {
      bf16x8 bfrag = *(const bf16x8*)(bs + nt * 512);
      acc[nt] = __builtin_amdgcn_mfma_f32_16x16x32_bf16(af, bfrag, acc[nt], 0, 0, 0);
    }
  }

  // denominator: rows keyed by m live in lanes {m, m+16, m+32, m+48}
  psum += __shfl_xor(psum, 16);
  psum += __shfl_xor(psum, 32);
  if (lane < 16) atomicAdd(&lsum[i0 + lane], psum);

  // numerator: C/D layout row=(lane>>4)*4+r, col=lane&15
  #pragma unroll
  for (int nt = 0; nt < 8; nt++) {
    #pragma unroll
    for (int r = 0; r < 4; r++) {
      atomicAdd(&num[(size_t)(i0 + q * 4 + r) * FO + nt * 16 + m], acc[nt][r]);
    }
  }
}

// ---------------------------------------------------------------------------
// Kernel 3: out = num / l, vectorized float4.
// ---------------------------------------------------------------------------
__global__ __launch_bounds__(256) void k_div(
    const float* __restrict__ num, const float* __restrict__ lsum,
    float* __restrict__ out)
{
  int idx = blockIdx.x * 256 + threadIdx.x;        // float4 index
  float4 v = ((const float4*)num)[idx];
  float inv = 1.0f / lsum[idx >> 5];               // 32 float4 per row
  float4 o;
  o.x = v.x * inv; o.y = v.y * inv; o.z = v.z * inv; o.w = v.w * inv;
  ((float4*)out)[idx] = o;
}

extern "C" void kernel_launch(void* const* d_in, const int* in_sizes, int n_in,
                              void* d_out, int out_size, void* d_ws, size_t ws_size,
                              hipStream_t stream) {
  const float* x     = (const float*)d_in[0];
  const float* adj   = (const float*)d_in[1];
  const float* W     = (const float*)d_in[2];
  const float* a_src = (const float*)d_in[3];
  const float* a_dst = (const float*)d_in[4];
  float* out = (float*)d_out;

  char* ws = (char*)d_ws;
  __bf16* Bp   = (__bf16*)ws;                                  // 2 MB
  float* f_src = (float*)(ws + 2097152);                       // 32 KB
  float* f_dst = (float*)(ws + 2097152 + 32768);               // 32 KB
  float* num   = (float*)(ws + 2097152 + 65536);               // 4 MB
  float* lsum  = (float*)(ws + 2097152 + 65536 + 4194304);     // 32 KB

  hipMemsetAsync(num, 0, 4194304 + 32768, stream);             // zero num + lsum
  hipLaunchKernelGGL(k_proj, dim3(512), dim3(256), 0, stream,
                     x, W, a_src, a_dst, Bp, f_src, f_dst);
  hipLaunchKernelGGL(k_attn, dim3(1024), dim3(256), 0, stream,
                     adj, Bp, f_src, f_dst, num, lsum);
  hipLaunchKernelGGL(k_div, dim3(1024), dim3(256), 0, stream,
                     num, lsum, out);
}